// Round 1
// baseline (247.516 us; speedup 1.0000x reference)
//
#include <hip/hip_runtime.h>
#include <stdint.h>
#include <stddef.h>

#define SEQ 2048
#define DM  1024
#define NH  16
#define HD  64
#define BS  2
#define PAD 72   // 64 + 8 bf16 pad -> 144B rows, 16B-aligned, 2-way-bank (free)

typedef __attribute__((ext_vector_type(8))) __bf16 bf16x8;
typedef __attribute__((ext_vector_type(4))) float  floatx4;
typedef __attribute__((ext_vector_type(4))) unsigned int uintx4;
typedef __attribute__((ext_vector_type(4))) unsigned short ushortx4;

__device__ inline unsigned short f2bf(float f) {
  union { float f; unsigned int u; } a; a.f = f;
  unsigned int u = a.u;
  return (unsigned short)((u + 0x7fffu + ((u >> 16) & 1u)) >> 16);  // RNE
}

__device__ inline bf16x8 ldb8(const unsigned short* p) { return *(const bf16x8*)p; }

// ---------------- fp32 -> bf16 cast ----------------
__global__ __launch_bounds__(256) void cast_bf16(const float* __restrict__ src,
                                                 unsigned short* __restrict__ dst) {
  int i = blockIdx.x * 256 + threadIdx.x;
  floatx4 v = ((const floatx4*)src)[i];
  ushortx4 o;
  o.x = f2bf(v.x); o.y = f2bf(v.y); o.z = f2bf(v.z); o.w = f2bf(v.w);
  ((ushortx4*)dst)[i] = o;
}

// ---------------- QKV projection GEMM: C = X @ W^T + b ----------------
// 128x128 tile, BK=32, 4 waves each 64x64 (4x4 of 16x16x32 MFMA).
// z=0 -> Qb [4096][1024], z=1 -> Kb [4096][1024], z=2 -> Vt [b][h][d][seq]
__global__ __launch_bounds__(256) void gemm_qkv(
    const unsigned short* __restrict__ Xb, const unsigned short* __restrict__ Wb,
    const float* __restrict__ bq, const float* __restrict__ bk, const float* __restrict__ bv,
    unsigned short* __restrict__ Qb, unsigned short* __restrict__ Kb,
    unsigned short* __restrict__ Vt)
{
  __shared__ alignas(16) unsigned short Alds[128 * 32];  // 8KB, chunk-XOR-swizzled
  __shared__ alignas(16) unsigned short Blds[128 * 32];
  const int t = threadIdx.x;
  const int w = t >> 6, l = t & 63;
  const int lm = l & 15, lq = l >> 4;
  const int z = blockIdx.z;
  const size_t m0 = (size_t)blockIdx.y * 128;
  const size_t n0 = (size_t)blockIdx.x * 128;
  const unsigned short* W = Wb + (size_t)z * (1024 * 1024);
  const float* bias = (z == 0) ? bq : ((z == 1) ? bk : bv);

  // staging: chunk c (16B) sits at LDS byte c*16; holds global (row=c>>2, kq=(c&3)^((c>>3)&3))
  const int c0 = t, c1 = 256 + t;
  const int row0 = c0 >> 2, row1 = c1 >> 2;
  const int kq0 = (c0 & 3) ^ ((row0 >> 1) & 3);
  const int kq1 = (c1 & 3) ^ ((row1 >> 1) & 3);
  const unsigned short* gA0 = Xb + (m0 + row0) * 1024 + kq0 * 8;
  const unsigned short* gA1 = Xb + (m0 + row1) * 1024 + kq1 * 8;
  const unsigned short* gB0 = W + (n0 + row0) * 1024 + kq0 * 8;
  const unsigned short* gB1 = W + (n0 + row1) * 1024 + kq1 * 8;
  unsigned short* lA0 = Alds + (0 * 256 + w * 64) * 8;   // per-wave uniform LDS bases
  unsigned short* lA1 = Alds + (1 * 256 + w * 64) * 8;
  unsigned short* lB0 = Blds + (0 * 256 + w * 64) * 8;
  unsigned short* lB1 = Blds + (1 * 256 + w * 64) * 8;

  const int wr = (w >> 1) * 64, wc = (w & 1) * 64;
  const int sw = (lq ^ ((lm >> 1) & 3)) * 8;  // swizzled k-slot for frag reads
  floatx4 acc[4][4] = {};

  for (int k0 = 0; k0 < 1024; k0 += 32) {
    __syncthreads();
    __builtin_amdgcn_global_load_lds((const __attribute__((address_space(1))) void*)(gA0 + k0),
                                     (__attribute__((address_space(3))) void*)lA0, 16, 0, 0);
    __builtin_amdgcn_global_load_lds((const __attribute__((address_space(1))) void*)(gA1 + k0),
                                     (__attribute__((address_space(3))) void*)lA1, 16, 0, 0);
    __builtin_amdgcn_global_load_lds((const __attribute__((address_space(1))) void*)(gB0 + k0),
                                     (__attribute__((address_space(3))) void*)lB0, 16, 0, 0);
    __builtin_amdgcn_global_load_lds((const __attribute__((address_space(1))) void*)(gB1 + k0),
                                     (__attribute__((address_space(3))) void*)lB1, 16, 0, 0);
    __syncthreads();
    bf16x8 af[4], bfr[4];
#pragma unroll
    for (int i = 0; i < 4; i++)
      af[i] = ldb8(Alds + (wr + i * 16 + lm) * 32 + sw);
#pragma unroll
    for (int j = 0; j < 4; j++)
      bfr[j] = ldb8(Blds + (wc + j * 16 + lm) * 32 + sw);
#pragma unroll
    for (int i = 0; i < 4; i++)
#pragma unroll
      for (int j = 0; j < 4; j++)
        acc[i][j] = __builtin_amdgcn_mfma_f32_16x16x32_bf16(af[i], bfr[j], acc[i][j], 0, 0, 0);
  }

  // epilogue: C/D layout col=lane&15, row=quad*4+r
#pragma unroll
  for (int i = 0; i < 4; i++) {
#pragma unroll
    for (int j = 0; j < 4; j++) {
      const int ncol = (int)n0 + wc + j * 16 + lm;
      const float bval = bias[ncol];
#pragma unroll
      for (int r = 0; r < 4; r++) {
        const int mrow = (int)m0 + wr + i * 16 + lq * 4 + r;
        const unsigned short hb = f2bf(acc[i][j][r] + bval);
        if (z == 0) {
          Qb[(size_t)mrow * 1024 + ncol] = hb;
        } else if (z == 1) {
          Kb[(size_t)mrow * 1024 + ncol] = hb;
        } else {
          const int b_ = mrow >> 11, s = mrow & 2047;
          const int h = ncol >> 6, dc = ncol & 63;
          Vt[(size_t)((b_ * 16 + h) * 64 + dc) * SEQ + s] = hb;
        }
      }
    }
  }
}

// ---------------- flash attention ----------------
// grid (SEQ/64, NH, BS), block 256. Wave w handles queries q0 + w*16 .. +15.
__global__ __launch_bounds__(256) void attn(
    const unsigned short* __restrict__ Qb, const unsigned short* __restrict__ Kb,
    const unsigned short* __restrict__ Vt, const int* __restrict__ mask,
    float* __restrict__ out)
{
  __shared__ alignas(16) unsigned short Klds[64 * PAD];      // [key][d]
  __shared__ alignas(16) unsigned short Vlds[64 * PAD];      // [d][key] (transposed)
  __shared__ alignas(16) unsigned short Plds[4][16 * PAD];   // per-wave P buffer
  const int t = threadIdx.x, w = t >> 6, l = t & 63;
  const int lm = l & 15, lq = l >> 4;
  const int b = blockIdx.z, head = blockIdx.y;
  const int q0 = blockIdx.x * 64;
  const int hoff = head * 64;

  const unsigned short* Qrow = Qb + (size_t)(b * SEQ + q0 + w * 16 + lm) * DM + hoff;
  bf16x8 aQ0 = ldb8(Qrow + lq * 8);
  bf16x8 aQ1 = ldb8(Qrow + 32 + lq * 8);

  floatx4 oacc[4] = {};
  float mrow[4], lrow[4];
#pragma unroll
  for (int r = 0; r < 4; r++) { mrow[r] = -3.0e38f; lrow[r] = 0.0f; }

  const unsigned short* Kbase = Kb + (size_t)(b * SEQ) * DM + hoff;
  const unsigned short* Vbase = Vt + (size_t)((b * 16 + head) * 64) * SEQ;
  const int* mbase = mask + b * SEQ;
  const int srow = t >> 3;         // staging: 0..31
  const int sch = (t & 7) * 8;

  for (int kt = 0; kt < SEQ / 64; kt++) {
    const int k0 = kt * 64;
    __syncthreads();
#pragma unroll
    for (int rr = 0; rr < 2; rr++) {
      const int r2 = srow + rr * 32;
      uintx4 kv = *(const uintx4*)(Kbase + (size_t)(k0 + r2) * DM + sch);
      *(uintx4*)(Klds + r2 * PAD + sch) = kv;
      uintx4 vv = *(const uintx4*)(Vbase + (size_t)r2 * SEQ + k0 + sch);
      *(uintx4*)(Vlds + r2 * PAD + sch) = vv;
    }
    __syncthreads();

    // S = Q K^T  (A = Q[m=q][k=d], B[k=d][n=key] read from K[key][d])
    floatx4 sacc[4] = {};
#pragma unroll
    for (int jn = 0; jn < 4; jn++) {
      bf16x8 bK0 = ldb8(Klds + (jn * 16 + lm) * PAD + lq * 8);
      sacc[jn] = __builtin_amdgcn_mfma_f32_16x16x32_bf16(aQ0, bK0, sacc[jn], 0, 0, 0);
      bf16x8 bK1 = ldb8(Klds + (jn * 16 + lm) * PAD + 32 + lq * 8);
      sacc[jn] = __builtin_amdgcn_mfma_f32_16x16x32_bf16(aQ1, bK1, sacc[jn], 0, 0, 0);
    }

    // mask (before scale, per reference) + scale
#pragma unroll
    for (int jn = 0; jn < 4; jn++) {
      const int mk = mbase[k0 + jn * 16 + lm];
#pragma unroll
      for (int r = 0; r < 4; r++)
        sacc[jn][r] = mk ? sacc[jn][r] * 0.125f : -1.0e29f;
    }

    // online softmax: rows live on lanes sharing quad; reduce over lane&15
    float alpha[4], tsum[4];
#pragma unroll
    for (int r = 0; r < 4; r++) {
      float v0 = fmaxf(fmaxf(sacc[0][r], sacc[1][r]), fmaxf(sacc[2][r], sacc[3][r]));
#pragma unroll
      for (int d = 1; d < 16; d <<= 1) v0 = fmaxf(v0, __shfl_xor(v0, d, 64));
      const float mnew = fmaxf(mrow[r], v0);
      alpha[r] = __expf(mrow[r] - mnew);
      mrow[r] = mnew;
      tsum[r] = 0.0f;
    }
#pragma unroll
    for (int jn = 0; jn < 4; jn++)
#pragma unroll
      for (int r = 0; r < 4; r++) {
        const float p = __expf(sacc[jn][r] - mrow[r]);
        sacc[jn][r] = p;
        tsum[r] += p;
      }
#pragma unroll
    for (int r = 0; r < 4; r++) {
      float v0 = tsum[r];
#pragma unroll
      for (int d = 1; d < 16; d <<= 1) v0 += __shfl_xor(v0, d, 64);
      lrow[r] = lrow[r] * alpha[r] + v0;
    }
#pragma unroll
    for (int dn = 0; dn < 4; dn++)
#pragma unroll
      for (int r = 0; r < 4; r++) oacc[dn][r] *= alpha[r];

    // P: C-layout -> LDS [q][key] -> A-layout frags (within-wave only)
    unsigned short* P = &Plds[w][0];
#pragma unroll
    for (int jn = 0; jn < 4; jn++)
#pragma unroll
      for (int r = 0; r < 4; r++)
        P[(lq * 4 + r) * PAD + jn * 16 + lm] = f2bf(sacc[jn][r]);
    bf16x8 aP0 = ldb8(P + lm * PAD + lq * 8);
    bf16x8 aP1 = ldb8(P + lm * PAD + 32 + lq * 8);

    // O += P V   (B[k=key][n=d] read from Vlds[d][key])
#pragma unroll
    for (int dn = 0; dn < 4; dn++) {
      bf16x8 bv0 = ldb8(Vlds + (dn * 16 + lm) * PAD + lq * 8);
      oacc[dn] = __builtin_amdgcn_mfma_f32_16x16x32_bf16(aP0, bv0, oacc[dn], 0, 0, 0);
      bf16x8 bv1 = ldb8(Vlds + (dn * 16 + lm) * PAD + 32 + lq * 8);
      oacc[dn] = __builtin_amdgcn_mfma_f32_16x16x32_bf16(aP1, bv1, oacc[dn], 0, 0, 0);
    }
  }

  float* orow = out + (size_t)(b * SEQ + q0 + w * 16) * DM + hoff;
#pragma unroll
  for (int r = 0; r < 4; r++) {
    const float inv = 1.0f / lrow[r];
#pragma unroll
    for (int dn = 0; dn < 4; dn++)
      orow[(size_t)(lq * 4 + r) * DM + dn * 16 + lm] = oacc[dn][r] * inv;
  }
}

// ---------------- launch ----------------
extern "C" void kernel_launch(void* const* d_in, const int* in_sizes, int n_in,
                              void* d_out, int out_size, void* d_ws, size_t ws_size,
                              hipStream_t stream) {
  const float* x   = (const float*)d_in[0];
  const int*   msk = (const int*)d_in[1];
  const float* Wq  = (const float*)d_in[2];
  const float* bq  = (const float*)d_in[3];
  const float* Wk  = (const float*)d_in[4];
  const float* bk  = (const float*)d_in[5];
  const float* Wv  = (const float*)d_in[6];
  const float* bv  = (const float*)d_in[7];
  float* out = (float*)d_out;

  unsigned short* ws = (unsigned short*)d_ws;
  unsigned short* Xb = ws;                               // [4096][1024]
  unsigned short* Wb = Xb + (size_t)4096 * 1024;         // [3][1024][1024]
  unsigned short* Qb = Wb + (size_t)3 * 1024 * 1024;     // [4096][1024]
  unsigned short* Kb = Qb + (size_t)4096 * 1024;         // [4096][1024]
  unsigned short* Vt = Kb + (size_t)4096 * 1024;         // [2][16][64][2048]

  cast_bf16<<<4096, 256, 0, stream>>>(x, Xb);
  cast_bf16<<<1024, 256, 0, stream>>>(Wq, Wb);
  cast_bf16<<<1024, 256, 0, stream>>>(Wk, Wb + (size_t)1024 * 1024);
  cast_bf16<<<1024, 256, 0, stream>>>(Wv, Wb + (size_t)2 * 1024 * 1024);

  gemm_qkv<<<dim3(8, 32, 3), 256, 0, stream>>>(Xb, Wb, bq, bk, bv, Qb, Kb, Vt);

  attn<<<dim3(SEQ / 64, NH, BS), 256, 0, stream>>>(Qb, Kb, Vt, msk, out);
}